// Round 8
// baseline (11076.913 us; speedup 1.0000x reference)
//
#include <hip/hip_runtime.h>

// samx_qkv_1bit R8: key side batched via the chain-image identity.
//   chain(j_i) = [j] + dedup(tk-images of chain(j_{i-1})) + [root]
// The current suffix path lives in an LDS array, so the key side does ZERO
// pointer-chasing: pass A scans batch-loaded tk values of old-chain nodes
// (prefix tk:=j stores, find breaker t2/d), clone decided from st[d] loaded
// AFTER prefix stores (matches reference timing: clone copies post-update tr),
// pass B emits dedup'd images (redirect run tk:=bb stores) into the other
// chain buffer, pass C blind-stamps rlp1:=i+1 on the new chain (the former
// serial propagation walk). Query side: VERBATIM R5 (proven) — staged for R9.
// State word (R5-proven): tr0[11:0] tr1[23:12] fl[35:24] ml[47:36] rlp1[59:48]
//   0xFFF = absent/-1; rlp1 = last end pos + 1, 0 = none.
// LDS: st[4095]*8 = 32760 + chbuf 2*2050*2 = 8200  -> 40960 B EXACT
//   -> 4 blocks/CU, all 1024 rows (one per block) co-resident on 256 CUs.
// Chain length bound: suffix-path node lengths strictly decrease from
// ml[j]=i+1 to 0 -> <= 2049 entries. States <= 2n-1 = 4095.

#define NST 4095
#define TLEN 2048
#define CLEN 2050
#define CH 8

typedef unsigned long long u64;

__device__ __forceinline__ int fld(u64 w, int sh) { return (int)((w >> sh) & 0xFFFull); }
__device__ __forceinline__ u64 setf(u64 w, int sh, int v) {
  return (w & ~(0xFFFull << sh)) | ((u64)(unsigned)v << sh);
}

__global__ __launch_bounds__(64)
void samx_main(const float* __restrict__ q,
               const float* __restrict__ k,
               unsigned* __restrict__ outpos,
               int T, int C) {
  __shared__ u64 st[NST];
  __shared__ unsigned short chbuf[2][CLEN];

  const int row = blockIdx.x;
  const int b = row / C;
  const int c = row - b * C;
  const int lane = threadIdx.x;

  for (int s = lane; s < NST; s += 64) st[s] = 0x0000000FFFFFFFFFull;

  const size_t rowbase = (size_t)b * (size_t)T * (size_t)C + (size_t)c;
  const float* qr = q + rowbase;
  const float* kr = k + rowbase;
  unsigned* outr = outpos + rowbase;

  // Pre-binarize: lane L holds bits t = 32L..32L+31 of q and k.
  unsigned qw = 0u, kw = 0u;
  {
    const int t0 = lane * 32;
#pragma unroll 8
    for (int jj = 0; jj < 32; ++jj) {
      const int t = t0 + jj;
      if (qr[(size_t)t * C] > 0.0f) qw |= (1u << jj);
      if (kr[(size_t)t * C] > 0.0f) kw |= (1u << jj);
    }
  }
  __syncthreads();
  if (lane != 0) return;

  chbuf[0][0] = 0;  // initial chain = [root]
  int len = 1;

  int g = 0;    // last state
  int mlg = 0;  // ml[g] (ml of an existing state never changes)
  int u = 1;    // next free state id
  int w = 0;    // query-match state
  int h = 0;    // query-match length

  for (int i = 0; i < T; ++i) {
    const unsigned qwi = (unsigned)__builtin_amdgcn_readlane((int)qw, i >> 5);
    const unsigned kwi = (unsigned)__builtin_amdgcn_readlane((int)kw, i >> 5);
    const int qs = (int)((qwi >> (i & 31)) & 1u);
    const int ks = (int)((kwi >> (i & 31)) & 1u);
    const int qsh = qs ? 12 : 0;
    const int ksh = ks ? 12 : 0;
    unsigned short* chA = chbuf[i & 1];         // current chain (read)
    unsigned short* chB = chbuf[(i & 1) ^ 1];   // next chain (write)

    // ================= QUERY SIDE: verbatim R5 (proven) =================
    int p = w, x = h;
    int ttrans = -1;
    for (;;) {
      if (p == 0xFFF) break;
      const u64 pw = st[p];
      const int t = fld(pw, qsh);
      if (t != 0xFFF) { ttrans = t; break; }
      const int mp = fld(pw, 36);
      if (x > mp) x = mp;
      p = fld(pw, 24);
    }
    if (p != 0xFFF) { p = ttrans; x = x + 1; }
    else            { p = 0;      x = 0; }

    int vst = p;
    for (;;) {
      const u64 vw = st[vst];
      const int fv = fld(vw, 24);
      if (fv == 0xFFF) break;
      const u64 fw = st[fv];
      if (fld(fw, 36) < x) break;
      vst = fv;
    }
    for (;;) {
      if (vst == 0xFFF) break;
      const u64 vw = st[vst];
      if (fld(vw, 36) > 0 && fld(vw, 48) != 0) break;
      vst = fld(vw, 24);
    }
    unsigned vidx = 0u;
    if (vst != 0xFFF) vidx = (unsigned)fld(st[vst], 48);
    outr[(size_t)i * C] = vidx;  // fire-and-forget
    w = p; h = x;

    // ================= KEY SIDE: batched over the chain =================
    const int j = u++;
    const int mlj = mlg + 1;

    // ---- PASS A: scan old chain; prefix tk:=j stores; find breaker ----
    int t2 = -1, d = -1, mlp = 0;
    {
      int t = 0;
      while (t < len && t2 < 0) {
        unsigned short ids[CH]; u64 wd[CH];
#pragma unroll
        for (int a = 0; a < CH; ++a) {
          int tt = t + a; if (tt > len - 1) tt = len - 1;
          ids[a] = chA[tt];
        }
#pragma unroll
        for (int a = 0; a < CH; ++a) wd[a] = st[ids[a]];
#pragma unroll
        for (int a = 0; a < CH; ++a) {
          if (t + a < len && t2 < 0) {
            const int tv = fld(wd[a], ksh);
            if (tv != 0xFFF) { t2 = t + a; d = tv; mlp = fld(wd[a], 36); }
            else st[ids[a]] = setf(wd[a], ksh, j);  // tk[p]=j (blind, computed)
          }
        }
        t += CH;
      }
    }

    // ---- clone decision (st[d] read AFTER prefix stores: reference timing) ----
    int flj, bb = -1;
    if (t2 < 0) {
      flj = 0;
    } else {
      const u64 dw = st[d];
      const int mld = fld(dw, 36);
      if (mlp + 1 == mld) {
        flj = d;
      } else {
        bb = u++;                         // clone of d with length mlp+1
        st[bb] = setf(dw, 36, mlp + 1);   // tr,fl,rl copied (incl. fresh tk)
        st[d]  = setf(dw, 24, bb);        // fl[d] = bb (d keeps its rl)
        flj = bb;
      }
    }
    st[j] = 0xFFFFFFull | ((u64)flj << 24) | ((u64)mlj << 36) | ((u64)(i + 1) << 48);

    // ---- PASS B: emit new chain = [j] + dedup(images) + [root] ----
    int nc = 0;
    chB[nc++] = (unsigned short)j;
    {
      int prev = j;
      bool redir = (bb >= 0);  // redirect run: tk==d -> bb, contiguous from t2
      if (t2 >= 0) {
        int t = t2;
        while (t < len) {
          unsigned short ids[CH]; u64 wd[CH];
#pragma unroll
          for (int a = 0; a < CH; ++a) {
            int tt = t + a; if (tt > len - 1) tt = len - 1;
            ids[a] = chA[tt];
          }
#pragma unroll
          for (int a = 0; a < CH; ++a) wd[a] = st[ids[a]];
#pragma unroll
          for (int a = 0; a < CH; ++a) {
            if (t + a < len) {
              const int tv = fld(wd[a], ksh);
              int img;
              if (redir && tv == d) {
                img = bb;
                st[ids[a]] = setf(wd[a], ksh, bb);  // redirect tk -> clone
              } else {
                redir = false;
                img = tv;
              }
              if (img != prev) { chB[nc++] = (unsigned short)img; prev = img; }
            }
          }
          t += CH;
        }
      }
    }
    chB[nc++] = 0;  // root terminates every suffix path

    // ---- PASS C: endpos propagation = blind rl stamps on new chain ----
    // (j already carries rlp1=i+1 in its creation word; stamp the rest.)
    {
      int t = 1;
      while (t < nc) {
        unsigned short ids[CH]; u64 wd[CH];
#pragma unroll
        for (int a = 0; a < CH; ++a) {
          int tt = t + a; if (tt > nc - 1) tt = nc - 1;
          ids[a] = chB[tt];
        }
#pragma unroll
        for (int a = 0; a < CH; ++a) wd[a] = st[ids[a]];
#pragma unroll
        for (int a = 0; a < CH; ++a) {
          if (t + a < nc) st[ids[a]] = setf(wd[a], 48, i + 1);
        }
        t += CH;
      }
    }

    g = j; mlg = mlj; len = nc;
  }
}

// Fully parallel epilogue: vidx (u32, = r+1, 0 = no match) -> sign*e.
__global__ __launch_bounds__(256)
void samx_epilogue(const float* __restrict__ v,
                   const float* __restrict__ e,
                   unsigned* __restrict__ out,
                   int T, int C, int total) {
  const int idx = blockIdx.x * 256 + threadIdx.x;
  if (idx >= total) return;
  const unsigned vidx = out[idx];
  const int c = idx % C;
  const int bi = idx / C;
  const int b = bi / T;
  const float ev = e[c];
  float val = -ev;  // y=0
  if (vidx != 0u) {
    if (v[((size_t)b * (size_t)T + (size_t)vidx) * (size_t)C + (size_t)c] > 0.0f)
      val = ev;
  }
  out[idx] = __float_as_uint(val);
}

extern "C" void kernel_launch(void* const* d_in, const int* in_sizes, int n_in,
                              void* d_out, int out_size, void* d_ws, size_t ws_size,
                              hipStream_t stream) {
  const float* q = (const float*)d_in[0];
  const float* k = (const float*)d_in[1];
  const float* v = (const float*)d_in[2];
  const float* e = (const float*)d_in[3];

  const int C = in_sizes[3];
  const int T = TLEN;
  const int B = in_sizes[0] / (T * C);
  const int total = out_size;

  samx_main<<<dim3(B * C), dim3(64), 0, stream>>>(q, k, (unsigned*)d_out, T, C);
  samx_epilogue<<<dim3((total + 255) / 256), dim3(256), 0, stream>>>(
      v, e, (unsigned*)d_out, T, C, total);
}